// Round 3
// baseline (219.066 us; speedup 1.0000x reference)
//
#include <hip/hip_runtime.h>

#define TILE  256
#define CIN   32
#define COUT  64
#define LSIZE 16384
#define NBITS 14

typedef float f32x4   __attribute__((ext_vector_type(4)));
typedef float vfloat4 __attribute__((ext_vector_type(4)));

__global__ __launch_bounds__(256, 4)
void hamming_fused(const float* __restrict__ x,
                   const float* __restrict__ w_self,
                   const float* __restrict__ w_bits,
                   const float* __restrict__ mix_w,
                   const float* __restrict__ mix_b,
                   float* __restrict__ out)
{
    __shared__ float xs[CIN][TILE];     // 32 KiB: x tile, then y (linear, round-0 layout)
    __shared__ float mws[CIN][COUT];    // 8 KiB, mws[c][o] = mix_w[o][c] (round-0 layout)

    const int tid  = threadIdx.x;       // 0..255
    const int lane = tid & 63;
    const int wv   = tid >> 6;          // wave id 0..3

    // ---- XCD-aware remap (round-0 verbatim): each XCD owns 4 whole batches;
    // a batch's 2 MiB x-slab stays resident in that XCD's 4 MiB L2.
    const int d    = blockIdx.x;        // 0..2047
    const int xcd  = d & 7;
    const int j    = d >> 3;
    const int b    = xcd * 4 + (j >> 6);
    const int tile = j & 63;
    const int base = tile * TILE;
    const float* xb = x + (size_t)b * CIN * LSIZE;

    // ---- stage mix_w transposed into LDS (round-0 verbatim, regular loads) ----
    #pragma unroll
    for (int i = 0; i < (CIN * COUT) / 256; ++i) {       // 8 iters
        int g = tid + i * 256;
        int o = g >> 5, c = g & 31;                      // mix_w[o][c]
        mws[c][o] = mix_w[g];
    }

    // ---- stage x tile via async global->LDS (16B per lane, wave-uniform base) ----
    #pragma unroll
    for (int i = 0; i < 8; ++i) {
        const int r = wv + i * 4;                        // wave-uniform row
        const float* src = xb + (size_t)r * LSIZE + base + lane * 4;
        __builtin_amdgcn_global_load_lds(
            (const __attribute__((address_space(1))) void*)src,
            (__attribute__((address_space(3))) void*)&xs[r][lane * 4],
            16, 0, 0);
    }

    const float ws = w_self[0];
    float wb[NBITS];
    #pragma unroll
    for (int k = 0; k < NBITS; ++k) wb[k] = w_bits[k];

    __syncthreads();                    // drains vmcnt + lgkmcnt: xs and mws ready

    // ---- stage 1: hypercube stencil, float4 form.
    // wave wv owns channels 8wv..8wv+7; each lane owns 4 consecutive columns.
    const int c0   = wv * 8;
    const int colb = lane * 4;

    f32x4 yv[8];
    #pragma unroll
    for (int cc = 0; cc < 8; cc += 2) {
        // prefetch 12 cross-tile dwordx4 (bits 8..13, L2-resident after remap)
        f32x4 pf[2][6];
        #pragma unroll
        for (int u = 0; u < 2; ++u) {
            const float* xr = xb + (size_t)(c0 + cc + u) * LSIZE;
            #pragma unroll
            for (int kk = 0; kk < 6; ++kk)
                pf[u][kk] = *(const f32x4*)(xr + ((base ^ (TILE << kk)) + colb));
        }
        #pragma unroll
        for (int u = 0; u < 2; ++u) {
            const int c = c0 + cc + u;
            const f32x4 s = *(const f32x4*)&xs[c][colb];
            f32x4 a = s * ws;
            // bits 0,1: neighbors inside the float4 -> register permutes
            a.x += wb[0] * s.y; a.y += wb[0] * s.x; a.z += wb[0] * s.w; a.w += wb[0] * s.z;
            a.x += wb[1] * s.z; a.y += wb[1] * s.w; a.z += wb[1] * s.x; a.w += wb[1] * s.y;
            // bits 2..7: in-tile, float4-contiguous under XOR
            #pragma unroll
            for (int k = 2; k < 8; ++k) {
                const f32x4 t = *(const f32x4*)&xs[c][colb ^ (1 << k)];
                a += wb[k] * t;
            }
            #pragma unroll
            for (int kk = 0; kk < 6; ++kk)
                a += wb[8 + kk] * pf[u][kk];
            yv[cc + u] = a * (1.0f / 15.0f);
        }
    }
    __syncthreads();                    // all xs reads done before overwrite

    // ---- write y back LINEAR (round-0 layout, no swizzle) ----
    #pragma unroll
    for (int cc = 0; cc < 8; ++cc)
        *(f32x4*)&xs[c0 + cc][colb] = yv[cc];
    __syncthreads();

    // ---- stage 2: channel mix, round-0 VALU code verbatim ----
    const int tx  = tid & 63;
    const int ty  = tid >> 6;
    const int cb2 = tx << 2;
    const int o0  = ty * 16;

    float4 acc[16];
    #pragma unroll
    for (int jj = 0; jj < 16; ++jj) {
        float bias = mix_b[o0 + jj];
        acc[jj] = make_float4(bias, bias, bias, bias);
    }

    #pragma unroll 4
    for (int c = 0; c < CIN; ++c) {
        float4 yc = *(float4*)&xs[c][cb2];
        #pragma unroll
        for (int j4 = 0; j4 < 4; ++j4) {
            float4 m = *(float4*)&mws[c][o0 + j4 * 4];   // wave-uniform
            acc[j4*4+0].x += m.x * yc.x; acc[j4*4+0].y += m.x * yc.y;
            acc[j4*4+0].z += m.x * yc.z; acc[j4*4+0].w += m.x * yc.w;
            acc[j4*4+1].x += m.y * yc.x; acc[j4*4+1].y += m.y * yc.y;
            acc[j4*4+1].z += m.y * yc.z; acc[j4*4+1].w += m.y * yc.w;
            acc[j4*4+2].x += m.z * yc.x; acc[j4*4+2].y += m.z * yc.y;
            acc[j4*4+2].z += m.z * yc.z; acc[j4*4+2].w += m.z * yc.w;
            acc[j4*4+3].x += m.w * yc.x; acc[j4*4+3].y += m.w * yc.y;
            acc[j4*4+3].z += m.w * yc.z; acc[j4*4+3].w += m.w * yc.w;
        }
    }

    // ---- store: coalesced float4, non-temporal (round-0 verbatim) ----
    float* ob = out + (size_t)b * COUT * LSIZE;
    #pragma unroll
    for (int jj = 0; jj < 16; ++jj) {
        vfloat4 v; v.x = acc[jj].x; v.y = acc[jj].y; v.z = acc[jj].z; v.w = acc[jj].w;
        vfloat4* p = (vfloat4*)(ob + (size_t)(o0 + jj) * LSIZE + base + cb2);
        __builtin_nontemporal_store(v, p);
    }
}

extern "C" void kernel_launch(void* const* d_in, const int* in_sizes, int n_in,
                              void* d_out, int out_size, void* d_ws, size_t ws_size,
                              hipStream_t stream) {
    const float* x      = (const float*)d_in[0];
    const float* w_self = (const float*)d_in[1];
    const float* w_bits = (const float*)d_in[2];
    const float* mix_w  = (const float*)d_in[3];
    const float* mix_b  = (const float*)d_in[4];
    float* out = (float*)d_out;

    hamming_fused<<<dim3(2048), 256, 0, stream>>>(x, w_self, w_bits, mix_w, mix_b, out);
}